// Round 2
// baseline (8403.520 us; speedup 1.0000x reference)
//
#include <hip/hip_runtime.h>
#include <math.h>

#define DMODEL 2048
#define NHEADS 16
#define DK     128
#define BATCH  4
#define SEQ    2048
#define MROWS  (BATCH*SEQ)   // 8192

// ---------------------------------------------------------------------------
// NT-GEMM tile core: C[m,n] = sum_k X[m,k] * W[n,k]
// X: [*,2048] row-major, W: [2048,2048] row-major. BM=BN=128, BK=16,
// 256 threads, 8x8 micro-tile. (unchanged from R1: ~73% of fp32 vector peak)
// ---------------------------------------------------------------------------
__device__ __forceinline__ void gemm_tile_nt(const float* __restrict__ X,
                                             const float* __restrict__ W,
                                             int bm, int bn,
                                             float (&c)[8][8]) {
    __shared__ float As[16][132];   // [k][m], pad 132 (16B-aligned rows)
    __shared__ float Bs[16][132];   // [k][n]

    const int t    = threadIdx.x;
    const int r0   = t >> 2;          // 0..63 (tile row for staging)
    const int q4   = (t & 3) * 4;     // k-quad 0,4,8,12
    const int lane = t & 63;
    const int wave = t >> 6;
    const int row0 = (wave >> 1) * 64 + (lane >> 3) * 8;  // 0..120
    const int col0 = (wave & 1)  * 64 + (lane & 7)  * 8;  // 0..120

    const float* Xa = X + (size_t)(bm + r0)      * DMODEL + q4;
    const float* Xb = X + (size_t)(bm + r0 + 64) * DMODEL + q4;
    const float* Wa = W + (size_t)(bn + r0)      * DMODEL + q4;
    const float* Wb = W + (size_t)(bn + r0 + 64) * DMODEL + q4;

    for (int kt = 0; kt < DMODEL; kt += 16) {
        const float4 xa = *(const float4*)(Xa + kt);
        const float4 xb = *(const float4*)(Xb + kt);
        const float4 wa = *(const float4*)(Wa + kt);
        const float4 wb = *(const float4*)(Wb + kt);
        __syncthreads();   // previous compute done reading LDS
        As[q4+0][r0] = xa.x; As[q4+1][r0] = xa.y; As[q4+2][r0] = xa.z; As[q4+3][r0] = xa.w;
        As[q4+0][r0+64] = xb.x; As[q4+1][r0+64] = xb.y; As[q4+2][r0+64] = xb.z; As[q4+3][r0+64] = xb.w;
        Bs[q4+0][r0] = wa.x; Bs[q4+1][r0] = wa.y; Bs[q4+2][r0] = wa.z; Bs[q4+3][r0] = wa.w;
        Bs[q4+0][r0+64] = wb.x; Bs[q4+1][r0+64] = wb.y; Bs[q4+2][r0+64] = wb.z; Bs[q4+3][r0+64] = wb.w;
        __syncthreads();
#pragma unroll
        for (int kk = 0; kk < 16; ++kk) {
            const float4 a0 = *(const float4*)&As[kk][row0];
            const float4 a1 = *(const float4*)&As[kk][row0 + 4];
            const float4 b0 = *(const float4*)&Bs[kk][col0];
            const float4 b1 = *(const float4*)&Bs[kk][col0 + 4];
            const float a[8] = {a0.x,a0.y,a0.z,a0.w,a1.x,a1.y,a1.z,a1.w};
            const float b[8] = {b0.x,b0.y,b0.z,b0.w,b1.x,b1.y,b1.z,b1.w};
#pragma unroll
            for (int i = 0; i < 8; ++i)
#pragma unroll
                for (int j = 0; j < 8; ++j)
                    c[i][j] += a[i] * b[j];
        }
    }
}

__global__ __launch_bounds__(256)
void qkv_proj_kernel(const float* __restrict__ x,
                     const float* __restrict__ wq,
                     const float* __restrict__ wk,
                     const float* __restrict__ wv,
                     float* __restrict__ Qb, float* __restrict__ Kb,
                     float* __restrict__ Vb) {
    const int g  = blockIdx.x >> 4;
    const int nb = blockIdx.x & 15;         // head index
    const int bm = blockIdx.y * 128;
    const float* W = (g == 0) ? wq : (g == 1) ? wk : wv;
    float* outb    = (g == 0) ? Qb : (g == 1) ? Kb : Vb;

    float c[8][8] = {};
    gemm_tile_nt(x, W, bm, nb * 128, c);

    const int lane = threadIdx.x & 63;
    const int wave = threadIdx.x >> 6;
    const int row0 = (wave >> 1) * 64 + (lane >> 3) * 8;
    const int col0 = (wave & 1)  * 64 + (lane & 7)  * 8;   // = dk base
#pragma unroll
    for (int i = 0; i < 8; ++i) {
        const int m  = bm + row0 + i;
        const int bb = m >> 11;           // /SEQ
        const int ss = m & 2047;
        float* dst = outb + ((size_t)(bb * NHEADS + nb) * SEQ + ss) * DK + col0;
        *(float4*)(dst)     = make_float4(c[i][0], c[i][1], c[i][2], c[i][3]);
        *(float4*)(dst + 4) = make_float4(c[i][4], c[i][5], c[i][6], c[i][7]);
    }
}

__global__ __launch_bounds__(256)
void out_proj_kernel(const float* __restrict__ A,
                     const float* __restrict__ wo,
                     float* __restrict__ out) {
    const int bn = blockIdx.x * 128;
    const int bm = blockIdx.y * 128;
    float c[8][8] = {};
    gemm_tile_nt(A, wo, bm, bn, c);

    const int lane = threadIdx.x & 63;
    const int wave = threadIdx.x >> 6;
    const int row0 = (wave >> 1) * 64 + (lane >> 3) * 8;
    const int col0 = (wave & 1)  * 64 + (lane & 7)  * 8;
#pragma unroll
    for (int i = 0; i < 8; ++i) {
        float* dst = out + (size_t)(bm + row0 + i) * DMODEL + bn + col0;
        *(float4*)(dst)     = make_float4(c[i][0], c[i][1], c[i][2], c[i][3]);
        *(float4*)(dst + 4) = make_float4(c[i][4], c[i][5], c[i][6], c[i][7]);
    }
}

// ---------------------------------------------------------------------------
// Flash attention, fp32, 4-query register blocking.
// Grid: (S/128, B*H). 256 threads. Thread t: qslot = t>>3 (0..31), dg = t&7.
// Thread owns queries {q0 + qslot + 32j : j<4} and dims {dg*4 + 32c + e}.
// Key tile = 16. Each ds_read_b128 of K/V feeds 4 queries => 2 FLOP/B
// (4x the R1 ratio). Scores butterfly-reduced over the 8 dg lanes.
// ---------------------------------------------------------------------------
__global__ __launch_bounds__(256, 2)
void attn_kernel(const float* __restrict__ Q, const float* __restrict__ Kg,
                 const float* __restrict__ Vg, float* __restrict__ O) {
    __shared__ float Ks[16][128];
    __shared__ float Vs[16][128];

    const int bh = blockIdx.y;           // b*16 + h
    const int q0 = blockIdx.x * 128;
    const int t  = threadIdx.x;
    const int qs = t >> 3;               // 0..31
    const int dg = t & 7;                // 0..7
    const float scale = 0.08838834764831845f;  // 1/sqrt(128)

    float4 qr[4][4];
#pragma unroll
    for (int j = 0; j < 4; ++j) {
        const float* Qrow = Q + ((size_t)bh * SEQ + q0 + qs + 32 * j) * DK;
#pragma unroll
        for (int c = 0; c < 4; ++c)
            qr[j][c] = *(const float4*)(Qrow + dg * 4 + c * 32);
    }

    float4 o[4][4];
#pragma unroll
    for (int j = 0; j < 4; ++j)
#pragma unroll
        for (int c = 0; c < 4; ++c) o[j][c] = make_float4(0.f, 0.f, 0.f, 0.f);
    float m[4] = {-1e30f, -1e30f, -1e30f, -1e30f};
    float l[4] = {0.f, 0.f, 0.f, 0.f};

    const float* Kbase = Kg + (size_t)bh * SEQ * DK;
    const float* Vbase = Vg + (size_t)bh * SEQ * DK;

    for (int kt = 0; kt < SEQ; kt += 16) {
        __syncthreads();   // previous iteration done reading tiles
#pragma unroll
        for (int r = 0; r < 2; ++r) {
            const int f   = t + 256 * r;      // 0..511
            const int row = f >> 5;           // 0..15
            const int c4  = f & 31;
            *(float4*)&Ks[row][c4 * 4] = ((const float4*)(Kbase + (size_t)(kt + row) * DK))[c4];
            *(float4*)&Vs[row][c4 * 4] = ((const float4*)(Vbase + (size_t)(kt + row) * DK))[c4];
        }
        __syncthreads();

        float s[4][16];
#pragma unroll
        for (int k = 0; k < 16; ++k) {
            float4 kv[4];
#pragma unroll
            for (int c = 0; c < 4; ++c) kv[c] = *(const float4*)&Ks[k][dg * 4 + c * 32];
#pragma unroll
            for (int j = 0; j < 4; ++j) {
                float acc = 0.f;
#pragma unroll
                for (int c = 0; c < 4; ++c) {
                    acc += qr[j][c].x * kv[c].x + qr[j][c].y * kv[c].y
                         + qr[j][c].z * kv[c].z + qr[j][c].w * kv[c].w;
                }
                s[j][k] = acc;
            }
        }
        // butterfly-reduce partial dots over the 8 dg lanes (in-wave)
#pragma unroll
        for (int j = 0; j < 4; ++j)
#pragma unroll
            for (int k = 0; k < 16; ++k) {
                float v = s[j][k];
                v += __shfl_xor(v, 1);
                v += __shfl_xor(v, 2);
                v += __shfl_xor(v, 4);
                s[j][k] = v * scale;
            }
        // online softmax (all 8 dg lanes compute identically)
#pragma unroll
        for (int j = 0; j < 4; ++j) {
            float mt = s[j][0];
#pragma unroll
            for (int k = 1; k < 16; ++k) mt = fmaxf(mt, s[j][k]);
            const float mnew = fmaxf(m[j], mt);
            const float corr = __expf(m[j] - mnew);
            float lsum = 0.f;
#pragma unroll
            for (int k = 0; k < 16; ++k) { s[j][k] = __expf(s[j][k] - mnew); lsum += s[j][k]; }
            l[j] = l[j] * corr + lsum;
#pragma unroll
            for (int c = 0; c < 4; ++c) {
                o[j][c].x *= corr; o[j][c].y *= corr;
                o[j][c].z *= corr; o[j][c].w *= corr;
            }
            m[j] = mnew;
        }
        // PV accumulate
#pragma unroll
        for (int k = 0; k < 16; ++k) {
            float4 vv[4];
#pragma unroll
            for (int c = 0; c < 4; ++c) vv[c] = *(const float4*)&Vs[k][dg * 4 + c * 32];
#pragma unroll
            for (int j = 0; j < 4; ++j) {
                const float p = s[j][k];
#pragma unroll
                for (int c = 0; c < 4; ++c) {
                    o[j][c].x += p * vv[c].x; o[j][c].y += p * vv[c].y;
                    o[j][c].z += p * vv[c].z; o[j][c].w += p * vv[c].w;
                }
            }
        }
    }

    const int bb = bh >> 4;
    const int h  = bh & 15;
#pragma unroll
    for (int j = 0; j < 4; ++j) {
        const float inv = 1.f / l[j];
        const size_t orow = ((size_t)bb * SEQ + q0 + qs + 32 * j) * DMODEL + (size_t)h * DK;
#pragma unroll
        for (int c = 0; c < 4; ++c) {
            const float4 ov = make_float4(o[j][c].x * inv, o[j][c].y * inv,
                                          o[j][c].z * inv, o[j][c].w * inv);
            *(float4*)(O + orow + dg * 4 + c * 32) = ov;
        }
    }
}

extern "C" void kernel_launch(void* const* d_in, const int* in_sizes, int n_in,
                              void* d_out, int out_size, void* d_ws, size_t ws_size,
                              hipStream_t stream) {
    const float* x  = (const float*)d_in[0];
    const float* wq = (const float*)d_in[1];
    const float* wk = (const float*)d_in[2];
    const float* wv = (const float*)d_in[3];
    const float* wo = (const float*)d_in[4];
    float* out = (float*)d_out;
    float* ws  = (float*)d_ws;

    // workspace layout (floats): Q,K,V in [B,H,S,DK]; attnO in [B,S,H*DK]
    float* Qb = ws;
    float* Kb = ws + (size_t)16777216;
    float* Vb = ws + (size_t)33554432;
    float* Ob = ws + (size_t)50331648;

    dim3 blk(256);
    qkv_proj_kernel<<<dim3(48, 64), blk, 0, stream>>>(x, wq, wk, wv, Qb, Kb, Vb);
    attn_kernel<<<dim3(SEQ / 128, BATCH * NHEADS), blk, 0, stream>>>(Qb, Kb, Vb, Ob);
    out_proj_kernel<<<dim3(16, 64), blk, 0, stream>>>(Ob, wo, out);
}